// Round 12
// baseline (1006.824 us; speedup 1.0000x reference)
//
#include <hip/hip_runtime.h>

typedef _Float16 f16x8 __attribute__((ext_vector_type(8)));
typedef _Float16 f16x4 __attribute__((ext_vector_type(4)));
typedef float f32x4 __attribute__((ext_vector_type(4)));

#define NTH 1024
#define SEQT 256
#define LD0 200
#define LD1 200
#define LD2 168

struct KArgs { const float* in[30]; float* out; };

__device__ __forceinline__ f32x4 mfma16(f16x8 a, f16x8 b, f32x4 c) {
  return __builtin_amdgcn_mfma_f32_16x16x32_f16(a, b, c, 0, 0, 0);
}

__device__ __forceinline__ unsigned cvt_pk_u32(float x, float y) {
  return __builtin_bit_cast(unsigned, __builtin_amdgcn_cvt_pkrtz(x, y));
}

// tanh(x) = 1 - 2/(1+2^(2*log2e*x)); sig(x) = 1/(1+2^(-log2e*x))
// returns 4 packed f16 (uint2) for a single ds_write_b64
__device__ __forceinline__ uint2 combine_u2(const f32x4 a[3]) {
  float h[4];
  #pragma unroll
  for (int q = 0; q < 4; ++q) {
    const float e1 = __builtin_amdgcn_exp2f(2.885390082f * a[0][q]);
    const float e2 = __builtin_amdgcn_exp2f(2.885390082f * a[1][q]);
    const float es = __builtin_amdgcn_exp2f(-1.442695041f * a[2][q]);
    const float ff1 = 1.0f - __fdividef(2.0f, 1.0f + e1);
    const float ff2 = 1.0f - __fdividef(2.0f, 1.0f + e2);
    const float ti  = __fdividef(1.0f, 1.0f + es);
    h[q] = ff1 + ti * (ff2 - ff1);
  }
  uint2 u;
  u.x = cvt_pk_u32(h[0], h[1]);
  u.y = cvt_pk_u32(h[2], h[3]);
  return u;
}

// one 3-mat tile (ff1*mask, ff2*mask, ta+tb) -> wW[m*KT+kt]
template<int KT>
__device__ __forceinline__ void load_tile(f16x8* wW, const float* W1, const float* W2,
                                          const float* Wa, const float* Wb,
                                          const float* Mk, int n, int CAT, int H, int kb) {
  #pragma unroll
  for (int kt = 0; kt < KT; ++kt) {
    #pragma unroll
    for (int m = 0; m < 3; ++m) {
      f16x8 f;
      #pragma unroll
      for (int j = 0; j < 8; ++j) {
        const int k = kt * 32 + kb + j;
        float v = 0.f;
        if (n < H && k < CAT) {
          if (m == 0)      v = W1[n*CAT+k] * Mk[n*CAT+k];
          else if (m == 1) v = W2[n*CAT+k] * Mk[n*CAT+k];
          else             v = Wa[n*CAT+k] + Wb[n*CAT+k];
        }
        f[j] = (_Float16)v;
      }
      wW[m*KT + kt] = f;
    }
  }
}

__device__ __forceinline__ void init3(f32x4 acc[3], const float* sb, int bs, int n0) {
  #pragma unroll
  for (int m = 0; m < 3; ++m)
    acc[m] = *reinterpret_cast<const f32x4*>(sb + m*bs + n0);
}

__device__ __forceinline__ f16x8 loadB8u(const _Float16* p) {  // 8B-aligned 16B
  const f16x4 a = *reinterpret_cast<const f16x4*>(p);
  const f16x4 b = *reinterpret_cast<const f16x4*>(p + 4);
  f16x8 v;
  v[0]=a[0]; v[1]=a[1]; v[2]=a[2]; v[3]=a[3];
  v[4]=b[0]; v[5]=b[1]; v[6]=b[2]; v[7]=b[3];
  return v;
}

__global__ __launch_bounds__(NTH, 4) void ncp_fused(KArgs args) {
  __shared__ __align__(16) _Float16 c0[2][16 * LD0];
  __shared__ __align__(16) _Float16 c1[2][16 * LD1];
  __shared__ __align__(16) _Float16 c2[2][16 * LD2];
  __shared__ __align__(16) _Float16 wt3[15 * 64 * 8];   // L2 tile-3 frags (wave 15)
  __shared__ __align__(16) _Float16 wfcs[8 * 64 * 8];   // FC frags: (ot*2+kt)*64+lane
  __shared__ float b0s[3 * 128], b1s[3 * 80], b2s[3 * 64], bfcs[64];

  const int tid  = threadIdx.x;
  const int wv   = tid >> 6;       // 16 waves
  const int lane = tid & 63;
  const int r    = lane & 15;      // batch row
  const int g    = lane >> 4;
  const int kb   = g * 8;
  const int n4g  = 4 * g;
  const int wgBase = blockIdx.x * 16;
  const float* __restrict__ xg = args.in[29];

  // ---------- per-wave resident weights (ONE tile-role each) ----------
  // wv 0..7 : L0 tile wv (KT=6); wv 8..12: L1 tile wv-8 (KT=6)
  // wv 13,14: L2 tile wv-13 (KT=5) + FC o-tiles (frags in LDS)
  // wv 15   : L2 tile 2 (regs) + tile 3 (LDS wt3)
  f16x8 wW[18];
  if (wv < 8) {
    load_tile<6>(wW, args.in[1], args.in[3], args.in[5], args.in[7], args.in[0],
                 wv*16 + r, 180, 116, kb);
  } else if (wv < 13) {
    load_tile<6>(wW, args.in[10], args.in[12], args.in[14], args.in[16], args.in[9],
                 (wv-8)*16 + r, 192, 76, kb);
  } else {
    load_tile<5>(wW, args.in[19], args.in[21], args.in[23], args.in[25], args.in[18],
                 (wv-13)*16 + r, 140, 64, kb);
  }

  // ---------- LDS init ----------
  for (int u = tid; u < 15 * 64; u += NTH) {    // L2 tile-3 frags
    const int ln = u & 63;
    const int ff = u >> 6;
    const int kt = ff % 5, m = ff / 5;
    const int n  = 48 + (ln & 15);
    const int kbb = (ln >> 4) * 8;
    f16x8 f;
    #pragma unroll
    for (int j = 0; j < 8; ++j) {
      const int k = kt*32 + kbb + j;
      float v = 0.f;
      if (k < 140) {
        if (m == 0)      v = args.in[19][n*140+k] * args.in[18][n*140+k];
        else if (m == 1) v = args.in[21][n*140+k] * args.in[18][n*140+k];
        else             v = args.in[23][n*140+k] + args.in[25][n*140+k];
      }
      f[j] = (_Float16)v;
    }
    *reinterpret_cast<f16x8*>(wt3 + (size_t)u * 8) = f;
  }
  for (int u = tid; u < 8 * 64; u += NTH) {     // FC frags
    const int ln = u & 63;
    const int ff = u >> 6;                       // ot*2+kt
    const int kt = ff & 1, ot = ff >> 1;
    f16x8 f;
    #pragma unroll
    for (int j = 0; j < 8; ++j)
      f[j] = (_Float16)args.in[27][(ot*16 + (ln & 15))*64 + kt*32 + (ln >> 4)*8 + j];
    *reinterpret_cast<f16x8*>(wfcs + (size_t)u * 8) = f;
  }
  if (tid < 128) {
    b0s[tid]       = (tid < 116) ? args.in[2][tid] : 0.f;
    b0s[128 + tid] = (tid < 116) ? args.in[4][tid] : 0.f;
    b0s[256 + tid] = (tid < 116) ? args.in[6][tid] + args.in[8][tid] : 0.f;
  }
  if (tid < 80) {
    b1s[tid]       = (tid < 76) ? args.in[11][tid] : 0.f;
    b1s[80 + tid]  = (tid < 76) ? args.in[13][tid] : 0.f;
    b1s[160 + tid] = (tid < 76) ? args.in[15][tid] + args.in[17][tid] : 0.f;
  }
  if (tid < 64) {
    b2s[tid]       = args.in[20][tid];
    b2s[64 + tid]  = args.in[22][tid];
    b2s[128 + tid] = args.in[24][tid] + args.in[26][tid];
    bfcs[tid]      = args.in[28][tid];
  }
  for (int i = tid; i < 2 * 16 * LD0; i += NTH) c0[0][i] = (_Float16)0.f;
  for (int i = tid; i < 2 * 16 * LD1; i += NTH) c1[0][i] = (_Float16)0.f;
  for (int i = tid; i < 2 * 16 * LD2; i += NTH) c2[0][i] = (_Float16)0.f;
  __syncthreads();
  // stage x(0): threads 0..511, float2 each
  const int rr = (tid & 511) >> 5, cc = (tid & 31) * 2;
  if (tid < 512) {
    const float2 v = *reinterpret_cast<const float2*>(
        xg + ((size_t)(wgBase + rr) * SEQT) * 64 + cc);
    *reinterpret_cast<unsigned*>(&c0[0][rr * LD0 + cc]) = cvt_pk_u32(v.x, v.y);
  }
  __syncthreads();

  const float* xp = xg + ((size_t)(wgBase + rr) * SEQT + 1) * 64 + cc;
  const int nb0 = wv*16 + n4g;
  const int nb1 = (wv-8)*16 + n4g;
  const int nb2 = (wv-13)*16 + n4g;
  const int otb = (wv >= 13) ? (wv - 13) : 0;
  float* outp = args.out + ((size_t)(wgBase + r) * SEQT) * 64 + otb * 32 + n4g;

#define PHASE(P, CUR, NXT) do {                                                 \
    const int p_ = (P);                                                         \
    float2 xv;                                                                  \
    const bool doX = (tid < 512) && (p_ < SEQT - 1);                            \
    if (doX) xv = *reinterpret_cast<const float2*>(xp);                         \
    if (wv < 8) {                                                               \
      if (p_ < SEQT) {                       /* L0 tile wv */                   \
        f32x4 a[3];                                                             \
        init3(a, b0s, 128, nb0);                                                \
        __builtin_amdgcn_s_setprio(1);                                          \
        _Pragma("unroll")                                                       \
        for (int kt = 0; kt < 6; ++kt) {                                        \
          const f16x8 b = *reinterpret_cast<const f16x8*>(&c0[CUR][r*LD0 + kt*32 + kb]); \
          _Pragma("unroll")                                                     \
          for (int m = 0; m < 3; ++m) a[m] = mfma16(wW[m*6 + kt], b, a[m]);     \
        }                                                                       \
        __builtin_amdgcn_s_setprio(0);                                          \
        const uint2 v = combine_u2(a);                                          \
        if (nb0 < 116) {                                                        \
          *reinterpret_cast<uint2*>(&c1[NXT][r*LD1 + nb0])      = v;            \
          *reinterpret_cast<uint2*>(&c0[NXT][r*LD0 + 64 + nb0]) = v;            \
        }                                                                       \
      }                                                                         \
    } else if (wv < 13) {                                                       \
      if (p_ >= 1 && p_ <= SEQT) {           /* L1 tile wv-8 */                 \
        f32x4 a[3];                                                             \
        init3(a, b1s, 80, nb1);                                                 \
        __builtin_amdgcn_s_setprio(1);                                          \
        _Pragma("unroll")                                                       \
        for (int kt = 0; kt < 6; ++kt) {                                        \
          const f16x8 b = *reinterpret_cast<const f16x8*>(&c1[CUR][r*LD1 + kt*32 + kb]); \
          _Pragma("unroll")                                                     \
          for (int m = 0; m < 3; ++m) a[m] = mfma16(wW[m*6 + kt], b, a[m]);     \
        }                                                                       \
        __builtin_amdgcn_s_setprio(0);                                          \
        const uint2 v = combine_u2(a);                                          \
        if (nb1 < 76) {                                                         \
          *reinterpret_cast<uint2*>(&c1[NXT][r*LD1 + 116 + nb1]) = v;           \
          *reinterpret_cast<uint2*>(&c2[NXT][r*LD2 + nb1])       = v;           \
        }                                                                       \
      }                                                                         \
    } else if (wv < 15) {                                                       \
      if (p_ >= 3 && p_ <= SEQT + 2) {       /* FC o-tiles on h2(p-3) */        \
        const int ot0 = (wv - 13) * 2;                                          \
        f32x4 fa0 = *reinterpret_cast<const f32x4*>(bfcs + ot0*16 + n4g);       \
        f32x4 fa1 = *reinterpret_cast<const f32x4*>(bfcs + ot0*16 + 16 + n4g);  \
        const f16x8 hb0 = loadB8u(&c2[CUR][r*LD2 + 76 + kb]);                   \
        const f16x8 hb1 = loadB8u(&c2[CUR][r*LD2 + 76 + 32 + kb]);              \
        const f16x8 wf00 = *reinterpret_cast<const f16x8*>(&wfcs[((size_t)((ot0*2    )*64 + lane))*8]); \
        const f16x8 wf01 = *reinterpret_cast<const f16x8*>(&wfcs[((size_t)((ot0*2 + 1)*64 + lane))*8]); \
        const f16x8 wf10 = *reinterpret_cast<const f16x8*>(&wfcs[((size_t)((ot0*2 + 2)*64 + lane))*8]); \
        const f16x8 wf11 = *reinterpret_cast<const f16x8*>(&wfcs[((size_t)((ot0*2 + 3)*64 + lane))*8]); \
        fa0 = mfma16(wf00, hb0, fa0); fa0 = mfma16(wf01, hb1, fa0);             \
        fa1 = mfma16(wf10, hb0, fa1); fa1 = mfma16(wf11, hb1, fa1);             \
        *reinterpret_cast<f32x4*>(outp)      = fa0;                             \
        *reinterpret_cast<f32x4*>(outp + 16) = fa1;                             \
        outp += 64;                                                             \
      }                                                                         \
      if (p_ >= 2 && p_ <= SEQT + 1) {       /* L2 tile wv-13 */                \
        f32x4 a[3];                                                             \
        init3(a, b2s, 64, nb2);                                                 \
        __builtin_amdgcn_s_setprio(1);                                          \
        _Pragma("unroll")                                                       \
        for (int kt = 0; kt < 5; ++kt) {                                        \
          const f16x8 b = *reinterpret_cast<const f16x8*>(&c2[CUR][r*LD2 + kt*32 + kb]); \
          _Pragma("unroll")                                                     \
          for (int m = 0; m < 3; ++m) a[m] = mfma16(wW[m*5 + kt], b, a[m]);     \
        }                                                                       \
        __builtin_amdgcn_s_setprio(0);                                          \
        const uint2 v = combine_u2(a);                                          \
        *reinterpret_cast<uint2*>(&c2[NXT][r*LD2 + 76 + nb2]) = v;              \
      }                                                                         \
    } else {                                                                    \
      if (p_ >= 2 && p_ <= SEQT + 1) {       /* L2 tiles 2 (regs) + 3 (LDS) */  \
        f32x4 a2[3], a3[3];                                                     \
        init3(a2, b2s, 64, 32 + n4g);                                           \
        init3(a3, b2s, 64, 48 + n4g);                                           \
        __builtin_amdgcn_s_setprio(1);                                          \
        _Pragma("unroll")                                                       \
        for (int kt = 0; kt < 5; ++kt) {                                        \
          const f16x8 b = *reinterpret_cast<const f16x8*>(&c2[CUR][r*LD2 + kt*32 + kb]); \
          _Pragma("unroll")                                                     \
          for (int m = 0; m < 3; ++m) {                                         \
            a2[m] = mfma16(wW[m*5 + kt], b, a2[m]);                             \
            const f16x8 af = *reinterpret_cast<const f16x8*>(&wt3[((size_t)((m*5 + kt)*64 + lane))*8]); \
            a3[m] = mfma16(af, b, a3[m]);                                       \
          }                                                                     \
        }                                                                       \
        __builtin_amdgcn_s_setprio(0);                                          \
        const uint2 v2 = combine_u2(a2);                                        \
        const uint2 v3 = combine_u2(a3);                                        \
        *reinterpret_cast<uint2*>(&c2[NXT][r*LD2 + 76 + 32 + n4g]) = v2;        \
        *reinterpret_cast<uint2*>(&c2[NXT][r*LD2 + 76 + 48 + n4g]) = v3;        \
      }                                                                         \
    }                                                                           \
    if (doX) {                               /* stage x(p+1) */                 \
      *reinterpret_cast<unsigned*>(&c0[NXT][rr * LD0 + cc]) = cvt_pk_u32(xv.x, xv.y); \
      xp += 64;                                                                 \
    }                                                                           \
    __syncthreads();                                                            \
  } while (0)

  // ---------- pipelined recurrence, 2 phases per iteration ----------
  // phase p: L0->h0(p), L1->h1(p-1), L2->h2(p-2), FC->y(p-3)
  #pragma unroll 1
  for (int pp = 0; pp < (SEQT + 4) / 2; ++pp) {   // p = 0..259; 259 is all-off
    PHASE(2 * pp,     0, 1);
    PHASE(2 * pp + 1, 1, 0);
  }
#undef PHASE
}

extern "C" void kernel_launch(void* const* d_in, const int* in_sizes, int n_in,
                              void* d_out, int out_size, void* d_ws, size_t ws_size,
                              hipStream_t stream) {
  KArgs args;
  for (int i = 0; i < 30; ++i) args.in[i] = (const float*)d_in[i];
  args.out = (float*)d_out;
  ncp_fused<<<dim3(32), dim3(NTH), 0, stream>>>(args);
}

// Round 13
// 717.330 us; speedup vs baseline: 1.4036x; 1.4036x over previous
//
#include <hip/hip_runtime.h>

typedef _Float16 f16x8 __attribute__((ext_vector_type(8)));
typedef _Float16 f16x4 __attribute__((ext_vector_type(4)));
typedef float f32x4 __attribute__((ext_vector_type(4)));

#define NTH 1024
#define SEQT 256
#define LD0 200
#define LD1 200
#define LD2 168

struct KArgs { const float* in[30]; float* out; };

__device__ __forceinline__ f32x4 mfma16(f16x8 a, f16x8 b, f32x4 c) {
  return __builtin_amdgcn_mfma_f32_16x16x32_f16(a, b, c, 0, 0, 0);
}

__device__ __forceinline__ unsigned cvt_pk_u32(float x, float y) {
  return __builtin_bit_cast(unsigned, __builtin_amdgcn_cvt_pkrtz(x, y));
}

// tanh(x) = 1 - 2/(1+2^(2*log2e*x)); sig(x) = 1/(1+2^(-log2e*x))
// returns 4 packed f16 (uint2) for a single ds_write_b64
__device__ __forceinline__ uint2 combine_u2(const f32x4 a[3]) {
  float h[4];
  #pragma unroll
  for (int q = 0; q < 4; ++q) {
    const float e1 = __builtin_amdgcn_exp2f(2.885390082f * a[0][q]);
    const float e2 = __builtin_amdgcn_exp2f(2.885390082f * a[1][q]);
    const float es = __builtin_amdgcn_exp2f(-1.442695041f * a[2][q]);
    const float ff1 = 1.0f - __fdividef(2.0f, 1.0f + e1);
    const float ff2 = 1.0f - __fdividef(2.0f, 1.0f + e2);
    const float ti  = __fdividef(1.0f, 1.0f + es);
    h[q] = ff1 + ti * (ff2 - ff1);
  }
  uint2 u;
  u.x = cvt_pk_u32(h[0], h[1]);
  u.y = cvt_pk_u32(h[2], h[3]);
  return u;
}

// one 3-mat tile (ff1*mask, ff2*mask, ta+tb) -> wW[m*KT+kt]
template<int KT>
__device__ __forceinline__ void load_tile(f16x8* wW, const float* W1, const float* W2,
                                          const float* Wa, const float* Wb,
                                          const float* Mk, int n, int CAT, int H, int kb) {
  #pragma unroll
  for (int kt = 0; kt < KT; ++kt) {
    #pragma unroll
    for (int m = 0; m < 3; ++m) {
      f16x8 f;
      #pragma unroll
      for (int j = 0; j < 8; ++j) {
        const int k = kt * 32 + kb + j;
        float v = 0.f;
        if (n < H && k < CAT) {
          if (m == 0)      v = W1[n*CAT+k] * Mk[n*CAT+k];
          else if (m == 1) v = W2[n*CAT+k] * Mk[n*CAT+k];
          else             v = Wa[n*CAT+k] + Wb[n*CAT+k];
        }
        f[j] = (_Float16)v;
      }
      wW[m*KT + kt] = f;
    }
  }
}

__device__ __forceinline__ void init3(f32x4 acc[3], const float* sb, int bs, int n0) {
  #pragma unroll
  for (int m = 0; m < 3; ++m)
    acc[m] = *reinterpret_cast<const f32x4*>(sb + m*bs + n0);
}

__device__ __forceinline__ f16x8 loadB8u(const _Float16* p) {  // 8B-aligned 16B
  const f16x4 a = *reinterpret_cast<const f16x4*>(p);
  const f16x4 b = *reinterpret_cast<const f16x4*>(p + 4);
  f16x8 v;
  v[0]=a[0]; v[1]=a[1]; v[2]=a[2]; v[3]=a[3];
  v[4]=b[0]; v[5]=b[1]; v[6]=b[2]; v[7]=b[3];
  return v;
}

__global__ __launch_bounds__(NTH, 4) void ncp_fused(KArgs args) {
  __shared__ __align__(16) _Float16 c0[2][16 * LD0];
  __shared__ __align__(16) _Float16 c1[2][16 * LD1];
  __shared__ __align__(16) _Float16 c2[2][16 * LD2];
  __shared__ __align__(16) _Float16 wt3[15 * 64 * 8];   // L2 tile-3 frags (wave 15)
  __shared__ __align__(16) _Float16 wfcs[8 * 64 * 8];   // FC frags: (ot*2+kt)*64+lane
  __shared__ float b0s[3 * 128], b1s[3 * 80], b2s[3 * 64], bfcs[64];

  const int tid  = threadIdx.x;
  const int wv   = tid >> 6;       // 16 waves
  const int lane = tid & 63;
  const int r    = lane & 15;      // batch row
  const int g    = lane >> 4;
  const int kb   = g * 8;
  const int n4g  = 4 * g;
  const int wgBase = blockIdx.x * 16;
  const float* __restrict__ xg = args.in[29];

  // ---------- per-wave resident weights (ONE tile-role each) ----------
  // wv 0..7 : L0 tile wv (KT=6); wv 8..12: L1 tile wv-8 (KT=6)
  // wv 13,14: L2 tile wv-13 (KT=5) + FC o-tiles (frags in LDS)
  // wv 15   : L2 tile 2 (regs) + tile 3 (LDS wt3)
  f16x8 wW[18];
  if (wv < 8) {
    load_tile<6>(wW, args.in[1], args.in[3], args.in[5], args.in[7], args.in[0],
                 wv*16 + r, 180, 116, kb);
  } else if (wv < 13) {
    load_tile<6>(wW, args.in[10], args.in[12], args.in[14], args.in[16], args.in[9],
                 (wv-8)*16 + r, 192, 76, kb);
  } else {
    load_tile<5>(wW, args.in[19], args.in[21], args.in[23], args.in[25], args.in[18],
                 (wv-13)*16 + r, 140, 64, kb);
  }

  // ---------- LDS init ----------
  for (int u = tid; u < 15 * 64; u += NTH) {    // L2 tile-3 frags
    const int ln = u & 63;
    const int ff = u >> 6;
    const int kt = ff % 5, m = ff / 5;
    const int n  = 48 + (ln & 15);
    const int kbb = (ln >> 4) * 8;
    f16x8 f;
    #pragma unroll
    for (int j = 0; j < 8; ++j) {
      const int k = kt*32 + kbb + j;
      float v = 0.f;
      if (k < 140) {
        if (m == 0)      v = args.in[19][n*140+k] * args.in[18][n*140+k];
        else if (m == 1) v = args.in[21][n*140+k] * args.in[18][n*140+k];
        else             v = args.in[23][n*140+k] + args.in[25][n*140+k];
      }
      f[j] = (_Float16)v;
    }
    *reinterpret_cast<f16x8*>(wt3 + (size_t)u * 8) = f;
  }
  for (int u = tid; u < 8 * 64; u += NTH) {     // FC frags
    const int ln = u & 63;
    const int ff = u >> 6;                       // ot*2+kt
    const int kt = ff & 1, ot = ff >> 1;
    f16x8 f;
    #pragma unroll
    for (int j = 0; j < 8; ++j)
      f[j] = (_Float16)args.in[27][(ot*16 + (ln & 15))*64 + kt*32 + (ln >> 4)*8 + j];
    *reinterpret_cast<f16x8*>(wfcs + (size_t)u * 8) = f;
  }
  if (tid < 128) {
    b0s[tid]       = (tid < 116) ? args.in[2][tid] : 0.f;
    b0s[128 + tid] = (tid < 116) ? args.in[4][tid] : 0.f;
    b0s[256 + tid] = (tid < 116) ? args.in[6][tid] + args.in[8][tid] : 0.f;
  }
  if (tid < 80) {
    b1s[tid]       = (tid < 76) ? args.in[11][tid] : 0.f;
    b1s[80 + tid]  = (tid < 76) ? args.in[13][tid] : 0.f;
    b1s[160 + tid] = (tid < 76) ? args.in[15][tid] + args.in[17][tid] : 0.f;
  }
  if (tid < 64) {
    b2s[tid]       = args.in[20][tid];
    b2s[64 + tid]  = args.in[22][tid];
    b2s[128 + tid] = args.in[24][tid] + args.in[26][tid];
    bfcs[tid]      = args.in[28][tid];
  }
  for (int i = tid; i < 2 * 16 * LD0; i += NTH) c0[0][i] = (_Float16)0.f;
  for (int i = tid; i < 2 * 16 * LD1; i += NTH) c1[0][i] = (_Float16)0.f;
  for (int i = tid; i < 2 * 16 * LD2; i += NTH) c2[0][i] = (_Float16)0.f;
  __syncthreads();
  // stage x(0): threads 0..511, float2 each
  const int rr = (tid & 511) >> 5, cc = (tid & 31) * 2;
  if (tid < 512) {
    const float2 v = *reinterpret_cast<const float2*>(
        xg + ((size_t)(wgBase + rr) * SEQT) * 64 + cc);
    *reinterpret_cast<unsigned*>(&c0[0][rr * LD0 + cc]) = cvt_pk_u32(v.x, v.y);
  }
  __syncthreads();

  const float* xp = xg + ((size_t)(wgBase + rr) * SEQT + 1) * 64 + cc;
  const int nb0 = wv*16 + n4g;
  const int nb1 = (wv-8)*16 + n4g;
  const int nb2 = (wv-13)*16 + n4g;
  const int otb = (wv >= 13) ? (wv - 13) : 0;
  float* outp = args.out + ((size_t)(wgBase + r) * SEQT) * 64 + otb * 32 + n4g;

  // ---------- pipelined recurrence: one barrier per phase ----------
  // phase p: L0->h0(p), L1->h1(p-1), L2->h2(p-2), FC->y(p-3)
  #pragma unroll 1
  for (int p = 0; p < SEQT + 3; ++p) {
    const int cur = p & 1, nxt = cur ^ 1;

    float2 xv;
    const bool doX = (tid < 512) && (p < SEQT - 1);
    if (doX) xv = *reinterpret_cast<const float2*>(xp);

    if (wv < 8) {
      if (p < SEQT) {                       // L0 tile wv
        f32x4 a[3];
        init3(a, b0s, 128, nb0);
        __builtin_amdgcn_s_setprio(1);
        #pragma unroll
        for (int kt = 0; kt < 6; ++kt) {
          const f16x8 b = *reinterpret_cast<const f16x8*>(&c0[cur][r*LD0 + kt*32 + kb]);
          #pragma unroll
          for (int m = 0; m < 3; ++m) a[m] = mfma16(wW[m*6 + kt], b, a[m]);
        }
        __builtin_amdgcn_s_setprio(0);
        const uint2 v = combine_u2(a);
        if (nb0 < 116) {
          *reinterpret_cast<uint2*>(&c1[nxt][r*LD1 + nb0])      = v;
          *reinterpret_cast<uint2*>(&c0[nxt][r*LD0 + 64 + nb0]) = v;
        }
      }
    } else if (wv < 13) {
      if (p >= 1 && p <= SEQT) {            // L1 tile wv-8
        f32x4 a[3];
        init3(a, b1s, 80, nb1);
        __builtin_amdgcn_s_setprio(1);
        #pragma unroll
        for (int kt = 0; kt < 6; ++kt) {
          const f16x8 b = *reinterpret_cast<const f16x8*>(&c1[cur][r*LD1 + kt*32 + kb]);
          #pragma unroll
          for (int m = 0; m < 3; ++m) a[m] = mfma16(wW[m*6 + kt], b, a[m]);
        }
        __builtin_amdgcn_s_setprio(0);
        const uint2 v = combine_u2(a);
        if (nb1 < 76) {
          *reinterpret_cast<uint2*>(&c1[nxt][r*LD1 + 116 + nb1]) = v;
          *reinterpret_cast<uint2*>(&c2[nxt][r*LD2 + nb1])       = v;
        }
      }
    } else if (wv < 15) {
      if (p >= 3) {                         // FC o-tiles (wv-13)*2,+1 on h2(p-3)
        const int ot0 = (wv - 13) * 2;
        f32x4 fa0 = *reinterpret_cast<const f32x4*>(bfcs + ot0*16 + n4g);
        f32x4 fa1 = *reinterpret_cast<const f32x4*>(bfcs + ot0*16 + 16 + n4g);
        const f16x8 hb0 = loadB8u(&c2[cur][r*LD2 + 76 + kb]);
        const f16x8 hb1 = loadB8u(&c2[cur][r*LD2 + 76 + 32 + kb]);
        const f16x8 wf00 = *reinterpret_cast<const f16x8*>(&wfcs[((size_t)((ot0*2    )*64 + lane))*8]);
        const f16x8 wf01 = *reinterpret_cast<const f16x8*>(&wfcs[((size_t)((ot0*2 + 1)*64 + lane))*8]);
        const f16x8 wf10 = *reinterpret_cast<const f16x8*>(&wfcs[((size_t)((ot0*2 + 2)*64 + lane))*8]);
        const f16x8 wf11 = *reinterpret_cast<const f16x8*>(&wfcs[((size_t)((ot0*2 + 3)*64 + lane))*8]);
        fa0 = mfma16(wf00, hb0, fa0); fa0 = mfma16(wf01, hb1, fa0);
        fa1 = mfma16(wf10, hb0, fa1); fa1 = mfma16(wf11, hb1, fa1);
        *reinterpret_cast<f32x4*>(outp)      = fa0;
        *reinterpret_cast<f32x4*>(outp + 16) = fa1;
        outp += 64;
      }
      if (p >= 2 && p <= SEQT + 1) {        // L2 tile wv-13
        f32x4 a[3];
        init3(a, b2s, 64, nb2);
        __builtin_amdgcn_s_setprio(1);
        #pragma unroll
        for (int kt = 0; kt < 5; ++kt) {
          const f16x8 b = *reinterpret_cast<const f16x8*>(&c2[cur][r*LD2 + kt*32 + kb]);
          #pragma unroll
          for (int m = 0; m < 3; ++m) a[m] = mfma16(wW[m*5 + kt], b, a[m]);
        }
        __builtin_amdgcn_s_setprio(0);
        const uint2 v = combine_u2(a);
        *reinterpret_cast<uint2*>(&c2[nxt][r*LD2 + 76 + nb2]) = v;
      }
    } else {
      if (p >= 2 && p <= SEQT + 1) {        // L2 tiles 2 (regs) + 3 (LDS), shared B
        f32x4 a2[3], a3[3];
        init3(a2, b2s, 64, 32 + n4g);
        init3(a3, b2s, 64, 48 + n4g);
        __builtin_amdgcn_s_setprio(1);
        #pragma unroll
        for (int kt = 0; kt < 5; ++kt) {
          const f16x8 b = *reinterpret_cast<const f16x8*>(&c2[cur][r*LD2 + kt*32 + kb]);
          #pragma unroll
          for (int m = 0; m < 3; ++m) {
            a2[m] = mfma16(wW[m*5 + kt], b, a2[m]);
            const f16x8 af = *reinterpret_cast<const f16x8*>(&wt3[((size_t)((m*5 + kt)*64 + lane))*8]);
            a3[m] = mfma16(af, b, a3[m]);
          }
        }
        __builtin_amdgcn_s_setprio(0);
        const uint2 v2 = combine_u2(a2);
        const uint2 v3 = combine_u2(a3);
        *reinterpret_cast<uint2*>(&c2[nxt][r*LD2 + 76 + 32 + n4g]) = v2;
        *reinterpret_cast<uint2*>(&c2[nxt][r*LD2 + 76 + 48 + n4g]) = v3;
      }
    }

    if (doX) {   // stage x(p+1) into c0[nxt][:,0:64)
      *reinterpret_cast<unsigned*>(&c0[nxt][rr * LD0 + cc]) = cvt_pk_u32(xv.x, xv.y);
      xp += 64;
    }
    __syncthreads();
  }
}

extern "C" void kernel_launch(void* const* d_in, const int* in_sizes, int n_in,
                              void* d_out, int out_size, void* d_ws, size_t ws_size,
                              hipStream_t stream) {
  KArgs args;
  for (int i = 0; i < 30; ++i) args.in[i] = (const float*)d_in[i];
  args.out = (float*)d_out;
  ncp_fused<<<dim3(32), dim3(NTH), 0, stream>>>(args);
}